// Round 4
// baseline (150.213 us; speedup 1.0000x reference)
//
#include <hip/hip_runtime.h>

#define IMG_SIZE 256
#define NPIX (IMG_SIZE * IMG_SIZE)
#define KSEL 5
#define BS 8
#define LL 64
#define LUSED 63                 // row l=63's top-k is discarded by the roll
#define NTHREADS 256
#define SPLIT 2                  // chunks per row
#define CHUNK_PX (NPIX / SPLIT)  // 32768
#define CHUNK_V4 (CHUNK_PX / 4)  // 8192 float4
#define ITERS (CHUNK_V4 / NTHREADS)   // 32
#define NROWS (BS * LUSED)       // 504
#define NBLOCKS (NROWS * SPLIT)  // 1008
#define COUNTER_OFF 40960        // keys = 504*2*5*8 = 40320 B, counter after

typedef unsigned long long ull;

// Key = (f32 dist bits << 32) | pixel_idx, reinterpreted as double.
// dist >= 0 and <= 3.0 -> high u64 bit 0, "exponent" field <= 0x409 -> the
// value is a positive, finite, non-NaN double, and IEEE f64 ordering equals
// u64 ordering. So v_min_f64 / v_max_f64 implement exact (dist, idx)
// lexicographic min/max in ONE instruction each.
__device__ __forceinline__ double pack_key(float s, int pix) {
    ull u = ((ull)__float_as_uint(s) << 32) | (unsigned int)pix;
    return __longlong_as_double((long long)u);
}

__device__ __forceinline__ float dist3(float r0, float r1, float r2,
                                       float c0, float c1, float c2) {
    // Match numpy f32 exactly: no FMA contraction, ((d0^2+d1^2)+d2^2).
    float d0 = __fsub_rn(r0, c0);
    float d1 = __fsub_rn(r1, c1);
    float d2 = __fsub_rn(r2, c2);
    return __fadd_rn(__fadd_rn(__fmul_rn(d0, d0), __fmul_rn(d1, d1)),
                     __fmul_rn(d2, d2));
}

// Branchless sorted-insert via f64 min/max: lad[] ascending, evict the max.
__device__ __forceinline__ void ins(double lad[KSEL], double key) {
    #pragma unroll
    for (int j = 0; j < KSEL; ++j) {
        double m = fmin(lad[j], key);
        key = fmax(lad[j], key);
        lad[j] = m;
    }
}

// Merge two ascending 5-lists, keep smallest 5 into a.
__device__ __forceinline__ void merge5(double* a, const double* b) {
    double out[KSEL];
    int ia = 0, ib = 0;
    #pragma unroll
    for (int j = 0; j < KSEL; ++j) {
        const double va = a[ia], vb = b[ib];
        const bool ta = va <= vb;
        out[j] = ta ? va : vb;
        ia += ta ? 1 : 0;
        ib += ta ? 0 : 1;
    }
    #pragma unroll
    for (int j = 0; j < KSEL; ++j) a[j] = out[j];
}

#define DINF __longlong_as_double(0x7FF0000000000000LL)   // +inf, > any key

// Fused: one block per (row, chunk) scans its half-image; the LAST block to
// finish also performs the epilogue (merge chunks, roll, min-dist, mean).
__global__ __launch_bounds__(NTHREADS)
void cc_loss_kernel(const float* __restrict__ preds,
                    const float* __restrict__ imgs,
                    double* __restrict__ keys,
                    int* __restrict__ counter,
                    float* __restrict__ out) {
    const int bx = blockIdx.x;
    const int chunk = bx & (SPLIT - 1);
    const int row = bx >> 1;              // 0..503
    const int b = row / LUSED;
    const int l = row % LUSED;
    const int t = threadIdx.x;

    // Scrambled pooled indexing: flat i = l*bs + b; pos from preds[i//64, i%64].
    const int i = l * BS + b;
    const int pb = i >> 6;
    const int pl = i & 63;
    const float px = preds[pb * (LL * 8) + pl * 8 + 0];
    const float py = preds[pb * (LL * 8) + pl * 8 + 1];

    // grid_sample nearest, align_corners=False, zeros padding.
    const float cx = __fsub_rn(__fmul_rn(px, 256.0f), 0.5f);
    const float cy = __fsub_rn(__fmul_rn(py, 256.0f), 0.5f);
    const int ix = (int)rintf(cx);        // round half to even == jnp.rint
    const int iy = (int)rintf(cy);
    const bool valid = (ix >= 0) && (ix < IMG_SIZE) && (iy >= 0) && (iy < IMG_SIZE);
    const int ixc = min(max(ix, 0), IMG_SIZE - 1);
    const int iyc = min(max(iy, 0), IMG_SIZE - 1);
    const float vmul = valid ? 1.0f : 0.0f;

    const float* imgb = imgs + (size_t)b * 3 * NPIX;
    const float c0 = imgb[0 * NPIX + iyc * IMG_SIZE + ixc] * vmul;
    const float c1 = imgb[1 * NPIX + iyc * IMG_SIZE + ixc] * vmul;
    const float c2 = imgb[2 * NPIX + iyc * IMG_SIZE + ixc] * vmul;

    const float4* p0 = (const float4*)(imgb + 0 * NPIX);
    const float4* p1 = (const float4*)(imgb + 1 * NPIX);
    const float4* p2 = (const float4*)(imgb + 2 * NPIX);

    // Two independent ladders (even/odd pixels) -> 2x ILP on the min/max chain.
    double ladA[KSEL], ladB[KSEL];
    #pragma unroll
    for (int j = 0; j < KSEL; ++j) { ladA[j] = DINF; ladB[j] = DINF; }

    const int vbase = chunk * CHUNK_V4;
    #pragma unroll 2
    for (int it = 0; it < ITERS; ++it) {
        const int v = vbase + it * NTHREADS + t;
        const float4 r0 = p0[v];
        const float4 r1 = p1[v];
        const float4 r2 = p2[v];
        const int base = v * 4;
        ins(ladA, pack_key(dist3(r0.x, r1.x, r2.x, c0, c1, c2), base + 0));
        ins(ladB, pack_key(dist3(r0.y, r1.y, r2.y, c0, c1, c2), base + 1));
        ins(ladA, pack_key(dist3(r0.z, r1.z, r2.z, c0, c1, c2), base + 2));
        ins(ladB, pack_key(dist3(r0.w, r1.w, r2.w, c0, c1, c2), base + 3));
    }
    #pragma unroll
    for (int j = 0; j < KSEL; ++j) ins(ladA, ladB[j]);

    // Block-level merge of 256 sorted 5-lists.
    __shared__ double sk[NTHREADS * KSEL];
    #pragma unroll
    for (int j = 0; j < KSEL; ++j) sk[t * KSEL + j] = ladA[j];
    __syncthreads();
    for (int s = NTHREADS / 2; s > 0; s >>= 1) {
        if (t < s) {
            double a[KSEL], bb[KSEL];
            #pragma unroll
            for (int j = 0; j < KSEL; ++j) { a[j] = sk[t * KSEL + j]; bb[j] = sk[(t + s) * KSEL + j]; }
            merge5(a, bb);
            #pragma unroll
            for (int j = 0; j < KSEL; ++j) sk[t * KSEL + j] = a[j];
        }
        __syncthreads();
    }
    if (t < KSEL) {
        keys[((size_t)row * SPLIT + chunk) * KSEL + t] = sk[t];
    }

    // ---- last-block epilogue ----
    __shared__ int is_last;
    __threadfence();                       // release our keys device-wide
    if (t == 0) {
        const int prev = atomicAdd(counter, 1);
        is_last = (prev == NBLOCKS - 1);
    }
    __syncthreads();
    if (!is_last) return;
    __threadfence();                       // acquire everyone else's keys

    float acc = 0.0f;
    for (int r = t; r < NROWS; r += NTHREADS) {
        const int rb = r / LUSED;
        const int rl = r % LUSED;          // storage row rl feeds loss row rl+1
        double lad[KSEL];
        #pragma unroll
        for (int j = 0; j < KSEL; ++j) lad[j] = DINF;
        #pragma unroll
        for (int c = 0; c < SPLIT; ++c) {
            #pragma unroll
            for (int k = 0; k < KSEL; ++k) {
                ins(lad, keys[((size_t)r * SPLIT + c) * KSEL + k]);
            }
        }
        const int lp = rl + 1;
        const float qx = preds[rb * (LL * 8) + lp * 8 + 0];
        const float qy = preds[rb * (LL * 8) + lp * 8 + 1];
        float best = 3.4028235e38f;
        #pragma unroll
        for (int k = 0; k < KSEL; ++k) {
            const ull u = (ull)__double_as_longlong(lad[k]);
            const int idx = (int)(u & 0xFFFFFFFFULL);
            const float tx = (float)(idx & 255) * (1.0f / 256.0f);   // exact /256
            const float ty = (float)(idx >> 8) * (1.0f / 256.0f);
            const float dx = __fsub_rn(qx, tx);
            const float dy = __fsub_rn(qy, ty);
            const float dist = __fadd_rn(__fmul_rn(dx, dx), __fmul_rn(dy, dy));
            best = dist < best ? dist : best;   // first-min tie semantics
        }
        acc += best;
    }

    __shared__ float red[NTHREADS];
    red[t] = acc;
    __syncthreads();
    for (int s = NTHREADS / 2; s > 0; s >>= 1) {
        if (t < s) red[t] += red[t + s];
        __syncthreads();
    }
    if (t == 0) {
        out[0] = red[0] / (float)(BS * (LL - 1));
    }
}

extern "C" void kernel_launch(void* const* d_in, const int* in_sizes, int n_in,
                              void* d_out, int out_size, void* d_ws, size_t ws_size,
                              hipStream_t stream) {
    const float* preds = (const float*)d_in[0];   // (8, 64, 8) f32
    const float* imgs  = (const float*)d_in[1];   // (8, 3, 256, 256) f32
    float* out = (float*)d_out;                   // scalar f32
    double* keys = (double*)d_ws;                 // 504*2*5 doubles = 40320 B
    int* counter = (int*)((char*)d_ws + COUNTER_OFF);

    // d_ws is re-poisoned to 0xAA before every launch: zero the arrival counter.
    hipMemsetAsync(counter, 0, sizeof(int), stream);
    cc_loss_kernel<<<dim3(NBLOCKS), dim3(NTHREADS), 0, stream>>>(preds, imgs, keys, counter, out);
}

// Round 5
// 138.984 us; speedup vs baseline: 1.0808x; 1.0808x over previous
//
#include <hip/hip_runtime.h>

#define IMG_SIZE 256
#define NPIX (IMG_SIZE * IMG_SIZE)
#define KSEL 5
#define BS 8
#define LL 64
#define LUSED 63                 // row l=63's top-k is discarded by the roll
#define NTHREADS 256
#define RROWS 7                  // rows (same image) per block; 63 = 9*7
#define NGRP 9
#define SPLIT 8                  // chunks per image
#define CHUNK_V4 (NPIX / 4 / SPLIT)    // 2048 float4
#define ITERS (CHUNK_V4 / NTHREADS)    // 8
#define NROWS (BS * LUSED)       // 504
#define NBLOCKS (BS * NGRP * SPLIT)    // 576
#define CAP 48                   // candidate slots per (row, chunk)
#define FBIG 3.402823466e38f
#define UINF 0xFFFFFFFFFFFFFFFFULL
#define COUNTER_OFF (NROWS * SPLIT * KSEL * 8)   // keys bytes = 161280

typedef unsigned long long ull;

__device__ __forceinline__ float dist3(float r0, float r1, float r2,
                                       float c0, float c1, float c2) {
    // Match numpy f32 exactly: no FMA contraction, ((d0^2+d1^2)+d2^2).
    float d0 = __fsub_rn(r0, c0);
    float d1 = __fsub_rn(r1, c1);
    float d2 = __fsub_rn(r2, c2);
    return __fadd_rn(__fadd_rn(__fmul_rn(d0, d0), __fmul_rn(d1, d1)),
                     __fmul_rn(d2, d2));
}

// Sorted-insert of value k into ascending 5-list: 1 v_min + 4 v_med3, all
// independent (depth 1). Exact multiset of 5 smallest values.
__device__ __forceinline__ void vins(float l[KSEL], float k) {
    float b0 = fminf(l[0], k);
    float b1 = __builtin_amdgcn_fmed3f(l[0], l[1], k);
    float b2 = __builtin_amdgcn_fmed3f(l[1], l[2], k);
    float b3 = __builtin_amdgcn_fmed3f(l[2], l[3], k);
    float b4 = __builtin_amdgcn_fmed3f(l[3], l[4], k);
    l[0] = b0; l[1] = b1; l[2] = b2; l[3] = b3; l[4] = b4;
}

// Exact lexicographic (dist,idx) insert: u64 compare + selects, static idx.
__device__ __forceinline__ void uins(ull l[KSEL], ull k) {
    #pragma unroll
    for (int j = 0; j < KSEL; ++j) {
        const ull a = l[j];
        const bool lt = k < a;
        l[j] = lt ? k : a;
        k    = lt ? a : k;
    }
}

__device__ __forceinline__ ull pack_key(float d, int pix) {
    // d >= 0 -> uint bit order == float order; low bits = pixel idx -> jax
    // top_k lower-index-first tie-break.
    return ((ull)__float_as_uint(d) << 32) | (unsigned int)pix;
}

__global__ __launch_bounds__(NTHREADS)
void cc_loss_kernel(const float* __restrict__ preds,
                    const float* __restrict__ imgs,
                    ull* __restrict__ keys,
                    int* __restrict__ counter,
                    float* __restrict__ out) {
    const int bx = blockIdx.x;
    const int chunk = bx & (SPLIT - 1);
    const int grp = bx >> 3;
    const int b = grp / NGRP;
    const int g = grp % NGRP;
    const int t = threadIdx.x;
    const int wave = t >> 6;
    const int lane = t & 63;

    const float* imgb = imgs + (size_t)b * 3 * NPIX;

    // Pooled centers for the 7 rows this block serves.
    float c0[RROWS], c1[RROWS], c2[RROWS];
    #pragma unroll
    for (int r = 0; r < RROWS; ++r) {
        const int l = g * RROWS + r;
        // Scrambled pooled indexing: flat i = l*bs + b; pos from preds[i//64, i%64].
        const int i = l * BS + b;
        const int pb = i >> 6;
        const int pl = i & 63;
        const float px = preds[pb * (LL * 8) + pl * 8 + 0];
        const float py = preds[pb * (LL * 8) + pl * 8 + 1];
        const float cx = __fsub_rn(__fmul_rn(px, 256.0f), 0.5f);
        const float cy = __fsub_rn(__fmul_rn(py, 256.0f), 0.5f);
        const int ix = (int)rintf(cx);   // round half to even == jnp.rint
        const int iy = (int)rintf(cy);
        const bool valid = (ix >= 0) && (ix < IMG_SIZE) && (iy >= 0) && (iy < IMG_SIZE);
        const int ixc = min(max(ix, 0), IMG_SIZE - 1);
        const int iyc = min(max(iy, 0), IMG_SIZE - 1);
        const float vmul = valid ? 1.0f : 0.0f;
        c0[r] = imgb[0 * NPIX + iyc * IMG_SIZE + ixc] * vmul;
        c1[r] = imgb[1 * NPIX + iyc * IMG_SIZE + ixc] * vmul;
        c2[r] = imgb[2 * NPIX + iyc * IMG_SIZE + ixc] * vmul;
    }

    const float4* p0 = (const float4*)(imgb + 0 * NPIX);
    const float4* p1 = (const float4*)(imgb + 1 * NPIX);
    const float4* p2 = (const float4*)(imgb + 2 * NPIX);
    const int vbase = chunk * CHUNK_V4;

    // ---- Pass 1: per-thread 5-smallest VALUES per row (f32 min/med3 ladder).
    float lad[RROWS][KSEL];
    #pragma unroll
    for (int r = 0; r < RROWS; ++r)
        #pragma unroll
        for (int j = 0; j < KSEL; ++j) lad[r][j] = FBIG;

    #pragma unroll 2
    for (int it = 0; it < ITERS; ++it) {
        const int v = vbase + it * NTHREADS + t;
        const float4 r0 = p0[v];
        const float4 r1 = p1[v];
        const float4 r2 = p2[v];
        #pragma unroll
        for (int r = 0; r < RROWS; ++r) {
            vins(lad[r], dist3(r0.x, r1.x, r2.x, c0[r], c1[r], c2[r]));
            vins(lad[r], dist3(r0.y, r1.y, r2.y, c0[r], c1[r], c2[r]));
            vins(lad[r], dist3(r0.z, r1.z, r2.z, c0[r], c1[r], c2[r]));
            vins(lad[r], dist3(r0.w, r1.w, r2.w, c0[r], c1[r], c2[r]));
        }
    }

    // ---- Wave butterfly merge (all 64 lanes converge to wave's 5-list).
    #pragma unroll
    for (int m = 1; m <= 32; m <<= 1) {
        #pragma unroll
        for (int r = 0; r < RROWS; ++r) {
            float o[KSEL];
            #pragma unroll
            for (int j = 0; j < KSEL; ++j) o[j] = __shfl_xor(lad[r][j], m, 64);
            #pragma unroll
            for (int j = 0; j < KSEL; ++j) vins(lad[r], o[j]);
        }
    }

    // ---- Cross-wave: block-level v5 per row.
    __shared__ float swl[4][RROWS][KSEL];
    __shared__ float sv5[RROWS];
    __shared__ int scnt[RROWS];
    __shared__ ull scand[RROWS][CAP];
    if (lane == 0) {
        #pragma unroll
        for (int r = 0; r < RROWS; ++r)
            #pragma unroll
            for (int j = 0; j < KSEL; ++j) swl[wave][r][j] = lad[r][j];
    }
    __syncthreads();
    if (t < RROWS) {
        float m5[KSEL];
        #pragma unroll
        for (int j = 0; j < KSEL; ++j) m5[j] = FBIG;
        #pragma unroll
        for (int w = 0; w < 4; ++w)
            #pragma unroll
            for (int j = 0; j < KSEL; ++j) vins(m5, swl[w][t][j]);
        sv5[t] = m5[4];
        scnt[t] = 0;
    }
    __syncthreads();

    float v5l[RROWS];
    #pragma unroll
    for (int r = 0; r < RROWS; ++r) v5l[r] = sv5[r];

    // ---- Pass 2: re-scan, capture all pixels with dist <= v5 (exact ties kept).
    #pragma unroll 2
    for (int it = 0; it < ITERS; ++it) {
        const int v = vbase + it * NTHREADS + t;
        const float4 r0 = p0[v];
        const float4 r1 = p1[v];
        const float4 r2 = p2[v];
        const int base = v * 4;
        #pragma unroll
        for (int r = 0; r < RROWS; ++r) {
            const float d0 = dist3(r0.x, r1.x, r2.x, c0[r], c1[r], c2[r]);
            const float d1 = dist3(r0.y, r1.y, r2.y, c0[r], c1[r], c2[r]);
            const float d2 = dist3(r0.z, r1.z, r2.z, c0[r], c1[r], c2[r]);
            const float d3 = dist3(r0.w, r1.w, r2.w, c0[r], c1[r], c2[r]);
            const float vv = v5l[r];
            if (d0 <= vv || d1 <= vv || d2 <= vv || d3 <= vv) {   // execz-skipped
                if (d0 <= vv) { int s = atomicAdd(&scnt[r], 1); if (s < CAP) scand[r][s] = pack_key(d0, base + 0); }
                if (d1 <= vv) { int s = atomicAdd(&scnt[r], 1); if (s < CAP) scand[r][s] = pack_key(d1, base + 1); }
                if (d2 <= vv) { int s = atomicAdd(&scnt[r], 1); if (s < CAP) scand[r][s] = pack_key(d2, base + 2); }
                if (d3 <= vv) { int s = atomicAdd(&scnt[r], 1); if (s < CAP) scand[r][s] = pack_key(d3, base + 3); }
            }
        }
    }
    __syncthreads();

    // ---- Exact lexicographic top-5 over the few candidates; write to global.
    if (t < RROWS) {
        const int n = min(scnt[t], CAP);
        ull m[KSEL];
        #pragma unroll
        for (int j = 0; j < KSEL; ++j) m[j] = UINF;
        for (int i2 = 0; i2 < n; ++i2) uins(m, scand[t][i2]);
        const int row = b * LUSED + g * RROWS + t;
        #pragma unroll
        for (int j = 0; j < KSEL; ++j)
            keys[((size_t)row * SPLIT + chunk) * KSEL + j] = m[j];
    }

    // ---- Last-block epilogue.
    __shared__ int is_last;
    __threadfence();
    if (t == 0) {
        const int prev = atomicAdd(counter, 1);
        is_last = (prev == NBLOCKS - 1);
    }
    __syncthreads();
    if (!is_last) return;
    __threadfence();

    float acc = 0.0f;
    for (int r = t; r < NROWS; r += NTHREADS) {
        const int rb = r / LUSED;
        const int rl = r % LUSED;          // storage row rl feeds loss row rl+1
        ull m[KSEL];
        #pragma unroll
        for (int j = 0; j < KSEL; ++j) m[j] = UINF;
        #pragma unroll 1
        for (int c = 0; c < SPLIT; ++c)
            #pragma unroll
            for (int k = 0; k < KSEL; ++k)
                uins(m, keys[((size_t)r * SPLIT + c) * KSEL + k]);
        const int lp = rl + 1;
        const float qx = preds[rb * (LL * 8) + lp * 8 + 0];
        const float qy = preds[rb * (LL * 8) + lp * 8 + 1];
        float best = FBIG;
        #pragma unroll
        for (int k = 0; k < KSEL; ++k) {
            const int idx = (int)(m[k] & 0xFFFFFFFFULL);
            const float tx = (float)(idx & 255) * (1.0f / 256.0f);   // exact /256
            const float ty = (float)(idx >> 8) * (1.0f / 256.0f);
            const float dx = __fsub_rn(qx, tx);
            const float dy = __fsub_rn(qy, ty);
            const float dist = __fadd_rn(__fmul_rn(dx, dx), __fmul_rn(dy, dy));
            best = dist < best ? dist : best;   // first-min tie semantics
        }
        acc += best;
    }

    __shared__ float red[NTHREADS];
    red[t] = acc;
    __syncthreads();
    for (int s = NTHREADS / 2; s > 0; s >>= 1) {
        if (t < s) red[t] += red[t + s];
        __syncthreads();
    }
    if (t == 0) {
        out[0] = red[0] / (float)(BS * (LL - 1));
    }
}

extern "C" void kernel_launch(void* const* d_in, const int* in_sizes, int n_in,
                              void* d_out, int out_size, void* d_ws, size_t ws_size,
                              hipStream_t stream) {
    const float* preds = (const float*)d_in[0];   // (8, 64, 8) f32
    const float* imgs  = (const float*)d_in[1];   // (8, 3, 256, 256) f32
    float* out = (float*)d_out;                   // scalar f32
    ull* keys = (ull*)d_ws;                       // 504*8*5 u64 = 161280 B
    int* counter = (int*)((char*)d_ws + COUNTER_OFF);

    // d_ws is re-poisoned to 0xAA before every launch: zero the arrival counter.
    hipMemsetAsync(counter, 0, sizeof(int), stream);
    cc_loss_kernel<<<dim3(NBLOCKS), dim3(NTHREADS), 0, stream>>>(preds, imgs, keys, counter, out);
}